// Round 5
// baseline (206.792 us; speedup 1.0000x reference)
//
#include <hip/hip_runtime.h>

// x [B, NF, T] f32, durations [B, N] int -> out [B, NF, N] f32 (segment means of nonzeros)
#define BB 64
#define NF 64
#define TT 8192
#define NN 1024
#define G  (TT / 4)                 // 2048 granules of 4 floats
#define PAD(c) ((c) + ((c) >> 3))   // read addr 9t+j -> conflict-free
#define CSZ (PAD(G) + 1)            // 2305 (grand-total slot at PAD(G))

// One block per (b,nf) row. Phases:
//  P0: in-block scan of this batch's durations -> bs[0..N] (4 KB, L2-hot across 64 blocks/batch)
//  A : stream row (coalesced float4), granule sum/count -> padded LDS staging
//  C1: boundary remainder partials from GLOBAL x (row L1/L2-hot, right after stream)
//  B : block exclusive scan of 2048 granule sums (reg + wave shfl + wave combine)
//  C2: P[i] += scanned prefix at boundary granule
//  D : token mean = adjacent prefix difference, coalesced store
// LDS ~30.8 KB -> 5 blocks/CU (20 waves/CU) vs R4's 2.
__global__ __launch_bounds__(256, 5) void fused_kernel(const float* __restrict__ x,
                                                       const int* __restrict__ dur,
                                                       float* __restrict__ out) {
    const int row  = blockIdx.x;           // b*NF + nf
    const int b    = row >> 6;             // NF = 64
    const int t    = threadIdx.x;
    const int lane = t & 63;
    const int w    = t >> 6;

    __shared__ int   bs[NN + 1];           // 4.1 KB boundaries
    __shared__ float csum[CSZ];            // 9.2 KB granule sums -> exclusive scan
    __shared__ int   ccnt[CSZ];            // 9.2 KB granule counts -> scan
    __shared__ float P[NN + 1];            // 4.1 KB prefix sum at boundaries
    __shared__ float Kc[NN + 1];           // 4.1 KB prefix count at boundaries
    __shared__ float wsf[4];
    __shared__ int   wsi[4];

    // ---- P0: boundaries = inclusive scan of durations (4 per thread + wave shfl) ----
    const int4 d4 = ((const int4*)(dur + b * NN))[t];
    const int s0 = d4.x, s1 = s0 + d4.y, s2 = s1 + d4.z, s3 = s2 + d4.w;
    int wsum = s3;
#pragma unroll
    for (int d = 1; d < 64; d <<= 1) {
        int u = __shfl_up(wsum, d, 64);
        if (lane >= d) wsum += u;
    }
    if (lane == 63) wsi[w] = wsum;
    __syncthreads();
    int boff = 0;
#pragma unroll
    for (int i = 0; i < 4; ++i) if (i < w) boff += wsi[i];
    const int ebase = boff + wsum - s3;    // exclusive prefix for this thread's 4
    bs[4 * t + 1] = ebase + s0;
    bs[4 * t + 2] = ebase + s1;
    bs[4 * t + 3] = ebase + s2;
    bs[4 * t + 4] = ebase + s3;
    if (t == 0) bs[0] = 0;
    __syncthreads();                       // bs ready; wsi free for reuse

    // ---- A: stream row, granule partial sums into padded staging (coalesced) ----
    const float4* __restrict__ xv = (const float4*)(x + (size_t)row * TT);
#pragma unroll
    for (int k = 0; k < G / 256; ++k) {
        const int c = t + (k << 8);
        const float4 v = xv[c];
        csum[PAD(c)] = v.x + v.y + v.z + v.w;
        ccnt[PAD(c)] = (v.x != 0.f) + (v.y != 0.f) + (v.z != 0.f) + (v.w != 0.f);
    }

    // ---- C1: boundary remainder partials from global (row hot in L1/L2) ----
    for (int i = t; i <= NN; i += 256) {
        const int p = bs[i];               // in [0, T]
        const int g = p >> 2, r = p & 3;
        float part = 0.f, pc = 0.f;
        if (r) {
            const float4 v = xv[g];
            part = v.x; pc = (v.x != 0.f);
            if (r > 1) { part += v.y; pc += (v.y != 0.f); }
            if (r > 2) { part += v.z; pc += (v.z != 0.f); }
        }
        P[i] = part; Kc[i] = pc;
    }
    __syncthreads();                       // staging + partials complete

    // ---- B: block exclusive scan over 2048 granules; thread owns [8t, 8t+8) ----
    float sv[8]; int cv[8];
    float fs = 0.f; int cs = 0;
#pragma unroll
    for (int j = 0; j < 8; ++j) {
        const int c = (t << 3) + j;        // PAD(c) = 9t+j : all 32 banks
        fs += csum[PAD(c)];
        cs += ccnt[PAD(c)];
        sv[j] = fs; cv[j] = cs;
    }
    float ws = fs; int wc = cs;
#pragma unroll
    for (int d = 1; d < 64; d <<= 1) {
        float uf = __shfl_up(ws, d, 64);
        int   ui = __shfl_up(wc, d, 64);
        if (lane >= d) { ws += uf; wc += ui; }
    }
    if (lane == 63) { wsf[w] = ws; wsi[w] = wc; }
    __syncthreads();
    float woff = 0.f; int coff = 0;
#pragma unroll
    for (int i = 0; i < 4; ++i) if (i < w) { woff += wsf[i]; coff += wsi[i]; }
    const float fbase = woff + (ws - fs);
    const int   cbase = coff + (wc - cs);
#pragma unroll
    for (int j = 0; j < 8; ++j) {
        const int c = (t << 3) + j;
        csum[PAD(c)] = fbase + (j ? sv[j - 1] : 0.f);   // exclusive
        ccnt[PAD(c)] = cbase + (j ? cv[j - 1] : 0);
    }
    if (t == 255) { csum[PAD(G)] = woff + ws; ccnt[PAD(G)] = coff + wc; }
    __syncthreads();

    // ---- C2: add scanned prefix at each boundary granule ----
    for (int i = t; i <= NN; i += 256) {
        const int g = bs[i] >> 2;
        P[i]  += csum[PAD(g)];
        Kc[i] += (float)ccnt[PAD(g)];
    }
    __syncthreads();

    // ---- D: token means, coalesced ----
    float* orow = out + (size_t)row * NN;
#pragma unroll
    for (int k = 0; k < NN / 256; ++k) {
        const int n = t + (k << 8);
        const float s = P[n + 1] - P[n];
        const float c = Kc[n + 1] - Kc[n];
        orow[n] = (c != 0.f) ? (s / c) : 0.f;
    }
}

extern "C" void kernel_launch(void* const* d_in, const int* in_sizes, int n_in,
                              void* d_out, int out_size, void* d_ws, size_t ws_size,
                              hipStream_t stream) {
    const float* x   = (const float*)d_in[0];
    const int*   dur = (const int*)d_in[1];
    float*       out = (float*)d_out;
    fused_kernel<<<BB * NF, 256, 0, stream>>>(x, dur, out);
}